// Round 10
// baseline (762.141 us; speedup 1.0000x reference)
//
#include <hip/hip_runtime.h>
#include <hip/hip_bf16.h>
#include <math.h>

// Problem constants (fixed by the reference)
#define B_    2
#define N_    120000
#define S_    40000
#define M_    30000
#define V_    100000
#define H_    256
#define WD_   1024
#define HID_  128
#define NSC_  4
#define NCLS_ 20
#define BM_   60000    // B*M rows of the image branch
#define BS_   80000    // B*S sample rows
#define BN_   240000   // B*N point rows

typedef __attribute__((ext_vector_type(8))) short bfrag8;   // 8 bf16 MFMA A/B frag
typedef __attribute__((ext_vector_type(4))) float facc4;    // 4 f32 MFMA C/D frag
typedef __attribute__((ext_vector_type(4))) unsigned short usvec4;

__device__ __forceinline__ unsigned short f2bf(float f){
  unsigned u = __builtin_bit_cast(unsigned, f);
  u += 0x7fffu + ((u >> 16) & 1u);          // round-to-nearest-even
  return (unsigned short)(u >> 16);
}
__device__ __forceinline__ float bf2f(unsigned short s){
  return __builtin_bit_cast(float, ((unsigned)s) << 16);
}

// ---------------------------------------------------------------------------
// Front kernel: three independent jobs in disjoint block ranges (no LDS).
__global__ __launch_bounds__(256) void k_front(
    const float* __restrict__ img, const int* __restrict__ ptsimg,
    unsigned short* __restrict__ iap,
    const int* __restrict__ p2i, const int* __restrict__ si,
    const int* __restrict__ ci,
    int* __restrict__ win_p, int* __restrict__ win_s, int* __restrict__ win_c,
    const float* __restrict__ lW, const float* __restrict__ f1W,
    const float* __restrict__ f2W, const float* __restrict__ c1W,
    const float* __restrict__ c2W,
    unsigned short* __restrict__ lwT, unsigned short* __restrict__ f1T,
    unsigned short* __restrict__ f2T, unsigned short* __restrict__ c1T,
    unsigned short* __restrict__ c2T){
  int bid = blockIdx.x;
  if (bid < 938){                                // ---- winner scatters ----
    int t = bid * 256 + threadIdx.x;
    if (t < BM_) atomicMax(&win_p[(t / M_) * N_ + p2i[t]], t);
    if (t < BS_) atomicMax(&win_s[(t / S_) * N_ + si[t]], t);
    if (t < BN_) atomicMax(&win_c[ci[t]], t);
    return;
  }
  if (bid < 2228){                               // ---- weight prep ----
    int t = (bid - 938) * 256 + threadIdx.x;     // 330240 exact
    if (t < 65536){                              // leaner: 4 x [128][128]
      int i = t >> 14, r = t & 16383, n = r >> 7, k = r & 127;
      lwT[i * 16384 + n * 128 + k] = f2bf(lW[i * 16384 + k * 128 + n]);
    } else if (t < 196608){                      // fcs1: 4 x [128][256]
      int e = t - 65536;
      int i = e >> 15, r = e & 32767, n = r >> 8, k = r & 255;
      f1T[i * 32768 + n * 256 + k] = f2bf(f1W[i * 32768 + k * 128 + n]);
    } else if (t < 262144){                      // fcs2: 4 x [128][128]
      int e = t - 196608;
      int i = e >> 14, r = e & 16383, n = r >> 7, k = r & 127;
      f2T[i * 16384 + n * 128 + k] = f2bf(f2W[i * 16384 + k * 128 + n]);
    } else if (t < 327680){                      // cls_W1: [128][512]
      int e = t - 262144;
      int n = e >> 9, k = e & 511;
      c1T[n * 512 + k] = f2bf(c1W[k * 128 + n]);
    } else if (t < 330240){                      // cls_W2: [20][128]
      int e = t - 327680;
      int n = e >> 7, k = e & 127;
      c2T[n * 128 + k] = f2bf(c2W[k * NCLS_ + n]);
    }
    return;
  }
  {                                              // ---- img gather ----
    int t = (bid - 2228) * 256 + threadIdx.x;    // t = r0*32 + g, 3750 blocks
    int r0 = t >> 5, h4 = (t & 31) * 4;
    const size_t st = (size_t)H_ * WD_;
    #pragma unroll
    for (int half = 0; half < 2; half++){
      int row = r0 + half * 30000;               // b == half
      int r = ptsimg[row * 2 + 0];
      int c = ptsimg[row * 2 + 1];
      const float* base = img + (((size_t)half * HID_ + h4) * H_ + r) * WD_ + c;
      float v0 = base[0], v1 = base[st], v2 = base[2 * st], v3 = base[3 * st];
      usvec4 o = {f2bf(v0), f2bf(v1), f2bf(v2), f2bf(v3)};
      *(usvec4*)(iap + (size_t)row * HID_ + h4) = o;
    }
    return;
  }
}

// ---------------------------------------------------------------------------
// output_3d stream — standalone at full occupancy (zero LDS). 4 j per thread
// (20 gather chains), branch-free clamped loads, NT stores.
__global__ __launch_bounds__(256) void k_o3d(const float* __restrict__ samp,
    const int* __restrict__ win_s, const int* __restrict__ win_p,
    const unsigned short* __restrict__ iap, float* __restrict__ o3d){
  const facc4 zero = {0.f, 0.f, 0.f, 0.f};
  int t = blockIdx.x * 256 + threadIdx.x;       // 7500 blocks
  int jg = t >> 5, q = t & 31;
  int j0 = jg << 2;
  int sjv[4], pjv[4];
  #pragma unroll
  for (int jj = 0; jj < 4; jj++){ sjv[jj] = win_s[j0 + jj]; pjv[jj] = win_p[j0 + jj]; }
  facc4 iv[4];
  #pragma unroll
  for (int jj = 0; jj < 4; jj++){
    int p = pjv[jj] < 0 ? 0 : pjv[jj];
    usvec4 u = *(const usvec4*)(iap + (size_t)p * HID_ + q * 4);
    facc4 v = {bf2f(u.x), bf2f(u.y), bf2f(u.z), bf2f(u.w)};
    iv[jj] = pjv[jj] >= 0 ? v : zero;
  }
  #pragma unroll
  for (int i = 0; i < NSC_; i++){
    #pragma unroll
    for (int jj = 0; jj < 4; jj++){
      int s = sjv[jj] < 0 ? 0 : sjv[jj];
      facc4 sv = *(const facc4*)(samp + ((size_t)i * BS_ + s) * HID_ + q * 4);
      facc4 v = iv[jj] + (sjv[jj] >= 0 ? sv : zero);
      __builtin_nontemporal_store(v,
          (facc4*)(o3d + (size_t)(j0 + jj) * (NSC_ * HID_) + i * HID_ + q * 4));
    }
  }
}

// ---------------------------------------------------------------------------
// Fused per-row MLP + classifier, BARRIER-FREE main loop.
// B-fragments are read DIRECTLY from the pre-transposed global weights
// (16B/lane contiguous; a wave's 64 lanes tile 16 full 64B lines; all blocks
// read the same ~640KB -> L2-resident). No LDS weight staging, so the only
// LDS is the 16KB act buffer, which is WAVE-PRIVATE (each wave reads/writes
// rows [wv*16, wv*16+16) only) -> in-wave lgkmcnt ordering, no barriers.
// One __syncthreads before the cross-wave W2 epilogue.
// acc[ct] covers cols [ct*16, ct*16+16); D row = rowBase + kg*4 + r.
__global__ __launch_bounds__(256, 3) void k_fused(
    const float* __restrict__ samp, const unsigned short* __restrict__ iap,
    const int* __restrict__ win_p, const int* __restrict__ win_s,
    const int* __restrict__ win_c, const int* __restrict__ p2i,
    const int* __restrict__ ci, const float* __restrict__ imgf,
    const unsigned short* __restrict__ lwT, const float* __restrict__ lb,
    const unsigned short* __restrict__ f1T, const float* __restrict__ f1b,
    const unsigned short* __restrict__ f2T, const float* __restrict__ f2b,
    const unsigned short* __restrict__ c1T, const float* __restrict__ c1b,
    const unsigned short* __restrict__ c2T, const float* __restrict__ c2b,
    float* __restrict__ logits){
  __shared__ char lds[21504];                    // 16KB act + 5KB W2
  char* actL = lds;
  char* w2L  = lds + 16384;
  const int tid = threadIdx.x;
  const int lane = tid & 63, wv = tid >> 6;
  const int rl = lane & 15, kg = lane >> 4;
  const int kgo = kg * 8;
  const int rowBase = blockIdx.x * 64 + wv * 16;
  const int row = rowBase + rl;
  const bool rv = row < BM_;
  const int lr = wv * 16 + rl;
  const int myswz = (lr & 15) << 4;

  int sj = -1, pj = -1;
  if (rv){
    int b = row >= M_;
    int g = win_c[ci[b * N_ + p2i[row]]];
    sj = win_s[g]; pj = win_p[g];
  }
  const unsigned short* pp = iap + (size_t)(pj < 0 ? 0 : pj) * HID_;

  facc4 accC[8];
  #pragma unroll
  for (int a = 0; a < 8; a++) accC[a] = (facc4){0.f, 0.f, 0.f, 0.f};

  #pragma unroll 1
  for (int i = 0; i < NSC_; i++){
    // ---- A-frags: leaner input = samp_i[sj] + iap[pj] (iap reload: L1-hot) ----
    bfrag8 afrL[4];
    {
      const float* sp = samp + ((size_t)i * BS_ + (sj < 0 ? 0 : sj)) * HID_;
      #pragma unroll
      for (int kc = 0; kc < 4; kc++){
        int k0 = kc * 32 + kgo;
        facc4 s0 = {0,0,0,0}, s1 = {0,0,0,0};
        if (sj >= 0){ s0 = *(const facc4*)(sp + k0); s1 = *(const facc4*)(sp + k0 + 4); }
        float g0=0,g1=0,g2=0,g3=0,g4=0,g5=0,g6=0,g7=0;
        if (pj >= 0){
          usvec4 u0 = *(const usvec4*)(pp + k0);
          usvec4 u1 = *(const usvec4*)(pp + k0 + 4);
          g0=bf2f(u0.x); g1=bf2f(u0.y); g2=bf2f(u0.z); g3=bf2f(u0.w);
          g4=bf2f(u1.x); g5=bf2f(u1.y); g6=bf2f(u1.z); g7=bf2f(u1.w);
        }
        bfrag8 a;
        a[0]=(short)f2bf(s0.x+g0); a[1]=(short)f2bf(s0.y+g1);
        a[2]=(short)f2bf(s0.z+g2); a[3]=(short)f2bf(s0.w+g3);
        a[4]=(short)f2bf(s1.x+g4); a[5]=(short)f2bf(s1.y+g5);
        a[6]=(short)f2bf(s1.z+g6); a[7]=(short)f2bf(s1.w+g7);
        afrL[kc] = a;
      }
    }

    // ---- leaner: direct-B GEMM (K=128) ----
    facc4 accT[8];
    #pragma unroll
    for (int a = 0; a < 8; a++) accT[a] = (facc4){0.f, 0.f, 0.f, 0.f};
    {
      const char* wl = (const char*)(lwT + (size_t)i * 16384);
      #pragma unroll
      for (int kc = 0; kc < 4; kc++){
        int kb = (kc * 32 + kgo) << 1;
        #pragma unroll
        for (int ct = 0; ct < 8; ct++){
          bfrag8 b = *(const bfrag8*)(wl + (ct * 16 + rl) * 256 + kb);
          accT[ct] = __builtin_amdgcn_mfma_f32_16x16x32_bf16(afrL[kc], b, accT[ct], 0, 0, 0);
        }
      }
    }
    // fl = relu(accT + lb) -> act LDS (wave-private slice)
    {
      const float* bias = lb + i * HID_;
      #pragma unroll
      for (int ct = 0; ct < 8; ct++){
        int col = ct * 16 + rl;
        float bv = bias[col];
        #pragma unroll
        for (int r = 0; r < 4; r++){
          int ar = wv * 16 + kg * 4 + r;
          float v = accT[ct][r] + bv; v = v > 0.f ? v : 0.f;
          int byte = ar * 256 + col * 2;
          *(unsigned short*)(actL + (byte ^ ((ar & 15) << 4))) = f2bf(v);
        }
      }
    }
    // imgf A-frags
    bfrag8 afrI[4];
    {
      const float* a1 = imgf + ((size_t)i * BM_ + (rv ? row : 0)) * HID_;
      #pragma unroll
      for (int kc = 0; kc < 4; kc++){
        int k0 = kc * 32 + kgo;
        facc4 s0 = {0,0,0,0}, s1 = {0,0,0,0};
        if (rv){ s0 = *(const facc4*)(a1 + k0); s1 = *(const facc4*)(a1 + k0 + 4); }
        bfrag8 a;
        a[0]=(short)f2bf(s0.x); a[1]=(short)f2bf(s0.y); a[2]=(short)f2bf(s0.z); a[3]=(short)f2bf(s0.w);
        a[4]=(short)f2bf(s1.x); a[5]=(short)f2bf(s1.y); a[6]=(short)f2bf(s1.z); a[7]=(short)f2bf(s1.w);
        afrI[kc] = a;
      }
    }
    // fl A-frags from act LDS (in-wave ordering via lgkmcnt)
    bfrag8 afrF[4];
    #pragma unroll
    for (int kc = 0; kc < 4; kc++){
      int byteA = lr * 256 + ((kc * 32 + kgo) << 1);
      afrF[kc] = *(const bfrag8*)(actL + (byteA ^ myswz));
    }
    // ---- fcs1: direct-B GEMM (K=256, concat [imgf | fl]) ----
    facc4 accF[8];
    #pragma unroll
    for (int a = 0; a < 8; a++) accF[a] = (facc4){0.f, 0.f, 0.f, 0.f};
    {
      const char* w1 = (const char*)(f1T + (size_t)i * 32768);
      #pragma unroll
      for (int kc = 0; kc < 8; kc++){
        int kb = (kc * 32 + kgo) << 1;
        bfrag8 a = kc < 4 ? afrI[kc] : afrF[kc - 4];
        #pragma unroll
        for (int ct = 0; ct < 8; ct++){
          bfrag8 b = *(const bfrag8*)(w1 + (ct * 16 + rl) * 512 + kb);
          accF[ct] = __builtin_amdgcn_mfma_f32_16x16x32_bf16(a, b, accF[ct], 0, 0, 0);
        }
      }
    }
    // fc = accF + b1 -> bf16: keep packed in regs (for gate) + act LDS (for A)
    unsigned fcp[8][2];
    {
      const float* bias = f1b + i * HID_;
      #pragma unroll
      for (int ct = 0; ct < 8; ct++){
        int col = ct * 16 + rl;
        float bv = bias[col];
        unsigned short b0 = f2bf(accF[ct][0] + bv), b1 = f2bf(accF[ct][1] + bv);
        unsigned short b2 = f2bf(accF[ct][2] + bv), b3 = f2bf(accF[ct][3] + bv);
        fcp[ct][0] = (unsigned)b0 | ((unsigned)b1 << 16);
        fcp[ct][1] = (unsigned)b2 | ((unsigned)b3 << 16);
        unsigned short bb[4] = {b0, b1, b2, b3};
        #pragma unroll
        for (int r = 0; r < 4; r++){
          int ar = wv * 16 + kg * 4 + r;
          int byte = ar * 256 + col * 2;
          *(unsigned short*)(actL + (byte ^ ((ar & 15) << 4))) = bb[r];
        }
      }
    }
    // fc A-frags
    bfrag8 afrC[4];
    #pragma unroll
    for (int kc = 0; kc < 4; kc++){
      int byteA = lr * 256 + ((kc * 32 + kgo) << 1);
      afrC[kc] = *(const bfrag8*)(actL + (byteA ^ myswz));
    }
    // ---- fcs2: direct-B GEMM (K=128) ----
    #pragma unroll
    for (int a = 0; a < 8; a++) accT[a] = (facc4){0.f, 0.f, 0.f, 0.f};
    {
      const char* w2 = (const char*)(f2T + (size_t)i * 16384);
      #pragma unroll
      for (int kc = 0; kc < 4; kc++){
        int kb = (kc * 32 + kgo) << 1;
        #pragma unroll
        for (int ct = 0; ct < 8; ct++){
          bfrag8 b = *(const bfrag8*)(w2 + (ct * 16 + rl) * 256 + kb);
          accT[ct] = __builtin_amdgcn_mfma_f32_16x16x32_bf16(afrC[kc], b, accT[ct], 0, 0, 0);
        }
      }
    }
    // gate: fuse = relu(bf16(fc) * sigmoid(accT + b2)) -> act LDS
    {
      const float* bias2 = f2b + i * HID_;
      #pragma unroll
      for (int ct = 0; ct < 8; ct++){
        int col = ct * 16 + rl;
        float bv2 = bias2[col];
        #pragma unroll
        for (int r = 0; r < 4; r++){
          int ar = wv * 16 + kg * 4 + r;
          float tv = accT[ct][r] + bv2;
          float fw = 1.f / (1.f + expf(-tv));
          unsigned short fcb = (unsigned short)(fcp[ct][r >> 1] >> ((r & 1) * 16));
          float u = bf2f(fcb) * fw;
          u = u > 0.f ? u : 0.f;
          int byte = ar * 256 + col * 2;
          *(unsigned short*)(actL + (byte ^ ((ar & 15) << 4))) = f2bf(u);
        }
      }
    }
    // fuse A-frags
    bfrag8 afrU[4];
    #pragma unroll
    for (int kc = 0; kc < 4; kc++){
      int byteA = lr * 256 + ((kc * 32 + kgo) << 1);
      afrU[kc] = *(const bfrag8*)(actL + (byteA ^ myswz));
    }
    // ---- cls1 chunk i: accC += fuse @ W1[i*128:(i+1)*128, :] ----
    {
      const char* wc = (const char*)c1T + i * 256;
      #pragma unroll
      for (int kc = 0; kc < 4; kc++){
        int kb = (kc * 32 + kgo) << 1;
        #pragma unroll
        for (int ct = 0; ct < 8; ct++){
          bfrag8 b = *(const bfrag8*)(wc + (ct * 16 + rl) * 1024 + kb);
          accC[ct] = __builtin_amdgcn_mfma_f32_16x16x32_bf16(afrU[kc], b, accC[ct], 0, 0, 0);
        }
      }
    }
  }

  // ---- classifier epilogue: hid = relu(accC + c1b) -> act; W2 dot ----
  #pragma unroll
  for (int ct = 0; ct < 8; ct++){
    int col = ct * 16 + rl;
    float bv = c1b[col];
    #pragma unroll
    for (int r = 0; r < 4; r++){
      int ar = wv * 16 + kg * 4 + r;
      float v = accC[ct][r] + bv; v = v > 0.f ? v : 0.f;
      int byte = ar * 256 + col * 2;
      *(unsigned short*)(actL + (byte ^ ((ar & 15) << 4))) = f2bf(v);
    }
  }
  for (int c = tid; c < 320; c += 256)
    *(bfrag8*)(w2L + (c << 4)) = *(const bfrag8*)((const char*)c2T + (c << 4));
  __syncthreads();                               // the ONLY barrier
  {
    int lrd = tid >> 2, n0 = (tid & 3) * 5;
    int orow = blockIdx.x * 64 + lrd;
    if (orow < BM_){
      float accD[5];
      #pragma unroll
      for (int q = 0; q < 5; q++) accD[q] = c2b[n0 + q];
      #pragma unroll
      for (int k8 = 0; k8 < 16; k8++){
        int byteA = lrd * 256 + (k8 << 4);
        bfrag8 hv = *(const bfrag8*)(actL + (byteA ^ ((lrd & 15) << 4)));
        #pragma unroll
        for (int q = 0; q < 5; q++){
          bfrag8 w8 = *(const bfrag8*)(w2L + (n0 + q) * 256 + (k8 << 4));
          #pragma unroll
          for (int e = 0; e < 8; e++)
            accD[q] += bf2f((unsigned short)hv[e]) * bf2f((unsigned short)w8[e]);
        }
      }
      #pragma unroll
      for (int q = 0; q < 5; q++)
        logits[(size_t)orow * NCLS_ + n0 + q] = accD[q];
    }
  }
}

// ---------------------------------------------------------------------------
extern "C" void kernel_launch(void* const* d_in, const int* in_sizes, int n_in,
                              void* d_out, int out_size, void* d_ws, size_t ws_size,
                              hipStream_t stream){
  const float* samp = (const float*)d_in[1];   // pts_sample_feat (pts_feat_layers is dead)
  const float* img  = (const float*)d_in[2];
  const float* imgf = (const float*)d_in[3];
  const float* lW   = (const float*)d_in[4];
  const float* lb   = (const float*)d_in[5];
  const float* f1W  = (const float*)d_in[6];
  const float* f1b  = (const float*)d_in[7];
  const float* f2W  = (const float*)d_in[8];
  const float* f2b  = (const float*)d_in[9];
  const float* c1W  = (const float*)d_in[10];
  const float* c1b  = (const float*)d_in[11];
  const float* c2W  = (const float*)d_in[12];
  const float* c2b  = (const float*)d_in[13];
  const int* ptsimg = (const int*)d_in[14];
  const int* p2i    = (const int*)d_in[15];
  const int* si     = (const int*)d_in[16];
  const int* ci     = (const int*)d_in[17];

  char* ws = (char*)d_ws;
  int*   win_p = (int*)(ws + 0);                       //   960,000 B
  int*   win_s = (int*)(ws + 960000);                  //   960,000 B
  int*   win_c = (int*)(ws + 1920000);                 //   400,000 B
  unsigned short* iap = (unsigned short*)(ws + 2320128);    // 15,360,000 B
  unsigned short* lwT = (unsigned short*)(ws + 17680384);   // 131,072 B
  unsigned short* f1T = lwT + 65536;                        // 262,144 B
  unsigned short* f2T = f1T + 131072;                       // 131,072 B
  unsigned short* c1T = f2T + 65536;                        // 131,072 B
  unsigned short* c2T = c1T + 65536;                        //   5,120 B

  float* logits = (float*)d_out;
  float* o3d    = (float*)d_out + (size_t)BM_ * NCLS_;

  (void)hipMemsetAsync(ws, 0xFF, 2320000, stream);     // win_* = -1
  k_front<<<5978, 256, 0, stream>>>(img, ptsimg, iap, p2i, si, ci,
                                    win_p, win_s, win_c,
                                    lW, f1W, f2W, c1W, c2W,
                                    lwT, f1T, f2T, c1T, c2T);
  k_o3d  <<<7500, 256, 0, stream>>>(samp, win_s, win_p, iap, o3d);
  k_fused<<<938,  256, 0, stream>>>(samp, iap, win_p, win_s, win_c, p2i, ci,
                                    imgf, lwT, lb, f1T, f1b, f2T, f2b,
                                    c1T, c1b, c2T, c2b, logits);
}

// Round 11
// 464.346 us; speedup vs baseline: 1.6413x; 1.6413x over previous
//
#include <hip/hip_runtime.h>
#include <hip/hip_bf16.h>
#include <math.h>

// Problem constants (fixed by the reference)
#define B_    2
#define N_    120000
#define S_    40000
#define M_    30000
#define V_    100000
#define H_    256
#define WD_   1024
#define HID_  128
#define NSC_  4
#define NCLS_ 20
#define BM_   60000    // B*M rows of the image branch
#define BS_   80000    // B*S sample rows
#define BN_   240000   // B*N point rows

typedef __attribute__((ext_vector_type(8))) short bfrag8;   // 8 bf16 MFMA A/B frag
typedef __attribute__((ext_vector_type(4))) float facc4;    // 4 f32 MFMA C/D frag
typedef __attribute__((ext_vector_type(4))) unsigned short usvec4;

__device__ __forceinline__ unsigned short f2bf(float f){
  unsigned u = __builtin_bit_cast(unsigned, f);
  u += 0x7fffu + ((u >> 16) & 1u);          // round-to-nearest-even
  return (unsigned short)(u >> 16);
}
__device__ __forceinline__ float bf2f(unsigned short s){
  return __builtin_bit_cast(float, ((unsigned)s) << 16);
}

// Stage one 64-row n-half of a [.][nstride-byte] bf16 weight matrix into a
// 16KB LDS buffer (row stride 256B, XOR-swizzled). [verified r8/r9]
__device__ __forceinline__ void stageW(char* wbuf, const char* src, int nstride, int tid){
  #pragma unroll
  for (int c0 = 0; c0 < 4; c0++){
    int c = c0 * 256 + tid;
    int nloc = c >> 4, off = (c & 15) << 4;
    *(bfrag8*)(wbuf + (((nloc << 8) + off) ^ ((nloc & 7) << 4))) =
        *(const bfrag8*)(src + (size_t)nloc * nstride + off);
  }
}

// One n-half MFMA quad: acc4[ctl] covers cols h*64 + ctl*16 + rl. [verified r8/r9]
__device__ __forceinline__ void mfmaHalf(facc4* acc4, const bfrag8* afr,
                                         const char* wbuf, int rl, int kg){
  #pragma unroll
  for (int kc = 0; kc < 4; kc++){
    int k2 = (kc * 32 + kg * 8) << 1;
    #pragma unroll
    for (int ctl = 0; ctl < 4; ctl++){
      int nloc = ctl * 16 + rl;
      bfrag8 b = *(const bfrag8*)(wbuf + (((nloc << 8) + k2) ^ ((nloc & 7) << 4)));
      acc4[ctl] = __builtin_amdgcn_mfma_f32_16x16x32_bf16(afr[kc], b, acc4[ctl], 0, 0, 0);
    }
  }
}

// ---------------------------------------------------------------------------
// Front kernel: three independent jobs in disjoint block ranges (no LDS).
__global__ __launch_bounds__(256) void k_front(
    const float* __restrict__ img, const int* __restrict__ ptsimg,
    unsigned short* __restrict__ iap,
    const int* __restrict__ p2i, const int* __restrict__ si,
    const int* __restrict__ ci,
    int* __restrict__ win_p, int* __restrict__ win_s, int* __restrict__ win_c,
    const float* __restrict__ lW, const float* __restrict__ f1W,
    const float* __restrict__ f2W, const float* __restrict__ c1W,
    const float* __restrict__ c2W,
    unsigned short* __restrict__ lwT, unsigned short* __restrict__ f1T,
    unsigned short* __restrict__ f2T, unsigned short* __restrict__ c1T,
    unsigned short* __restrict__ c2T){
  int bid = blockIdx.x;
  if (bid < 938){                                // ---- winner scatters ----
    int t = bid * 256 + threadIdx.x;
    if (t < BM_) atomicMax(&win_p[(t / M_) * N_ + p2i[t]], t);
    if (t < BS_) atomicMax(&win_s[(t / S_) * N_ + si[t]], t);
    if (t < BN_) atomicMax(&win_c[ci[t]], t);
    return;
  }
  if (bid < 2228){                               // ---- weight prep ----
    int t = (bid - 938) * 256 + threadIdx.x;     // 330240 exact
    if (t < 65536){                              // leaner: 4 x [128][128]
      int i = t >> 14, r = t & 16383, n = r >> 7, k = r & 127;
      lwT[i * 16384 + n * 128 + k] = f2bf(lW[i * 16384 + k * 128 + n]);
    } else if (t < 196608){                      // fcs1: 4 x [128][256]
      int e = t - 65536;
      int i = e >> 15, r = e & 32767, n = r >> 8, k = r & 255;
      f1T[i * 32768 + n * 256 + k] = f2bf(f1W[i * 32768 + k * 128 + n]);
    } else if (t < 262144){                      // fcs2: 4 x [128][128]
      int e = t - 196608;
      int i = e >> 14, r = e & 16383, n = r >> 7, k = r & 127;
      f2T[i * 16384 + n * 128 + k] = f2bf(f2W[i * 16384 + k * 128 + n]);
    } else if (t < 327680){                      // cls_W1: [128][512]
      int e = t - 262144;
      int n = e >> 9, k = e & 511;
      c1T[n * 512 + k] = f2bf(c1W[k * 128 + n]);
    } else if (t < 330240){                      // cls_W2: [20][128]
      int e = t - 327680;
      int n = e >> 7, k = e & 127;
      c2T[n * 128 + k] = f2bf(c2W[k * NCLS_ + n]);
    }
    return;
  }
  {                                              // ---- img gather ----
    int t = (bid - 2228) * 256 + threadIdx.x;    // t = r0*32 + g, 3750 blocks
    int r0 = t >> 5, h4 = (t & 31) * 4;
    const size_t st = (size_t)H_ * WD_;
    #pragma unroll
    for (int half = 0; half < 2; half++){
      int row = r0 + half * 30000;               // b == half
      int r = ptsimg[row * 2 + 0];
      int c = ptsimg[row * 2 + 1];
      const float* base = img + (((size_t)half * HID_ + h4) * H_ + r) * WD_ + c;
      float v0 = base[0], v1 = base[st], v2 = base[2 * st], v3 = base[3 * st];
      usvec4 o = {f2bf(v0), f2bf(v1), f2bf(v2), f2bf(v3)};
      *(usvec4*)(iap + (size_t)row * HID_ + h4) = o;
    }
    return;
  }
}

// ---------------------------------------------------------------------------
// output_3d stream — standalone at full occupancy (zero LDS). 4 j per thread
// (20 gather chains), branch-free clamped loads, NT stores. [r9: ~82 us]
__global__ __launch_bounds__(256) void k_o3d(const float* __restrict__ samp,
    const int* __restrict__ win_s, const int* __restrict__ win_p,
    const unsigned short* __restrict__ iap, float* __restrict__ o3d){
  const facc4 zero = {0.f, 0.f, 0.f, 0.f};
  int t = blockIdx.x * 256 + threadIdx.x;       // 7500 blocks
  int jg = t >> 5, q = t & 31;
  int j0 = jg << 2;
  int sjv[4], pjv[4];
  #pragma unroll
  for (int jj = 0; jj < 4; jj++){ sjv[jj] = win_s[j0 + jj]; pjv[jj] = win_p[j0 + jj]; }
  facc4 iv[4];
  #pragma unroll
  for (int jj = 0; jj < 4; jj++){
    int p = pjv[jj] < 0 ? 0 : pjv[jj];
    usvec4 u = *(const usvec4*)(iap + (size_t)p * HID_ + q * 4);
    facc4 v = {bf2f(u.x), bf2f(u.y), bf2f(u.z), bf2f(u.w)};
    iv[jj] = pjv[jj] >= 0 ? v : zero;
  }
  #pragma unroll
  for (int i = 0; i < NSC_; i++){
    #pragma unroll
    for (int jj = 0; jj < 4; jj++){
      int s = sjv[jj] < 0 ? 0 : sjv[jj];
      facc4 sv = *(const facc4*)(samp + ((size_t)i * BS_ + s) * HID_ + q * 4);
      facc4 v = iv[jj] + (sjv[jj] >= 0 ? sv : zero);
      __builtin_nontemporal_store(v,
          (facc4*)(o3d + (size_t)(j0 + jj) * (NSC_ * HID_) + i * HID_ + q * 4));
    }
  }
}

// ---------------------------------------------------------------------------
// Per-scale MLP (1 scale per block, i = bid&3). LDS 32KB = 16KB n-half weight
// buffer + 16KB act buffer -> 5 blocks/CU (vs round 6's 48KB / 3 blocks).
// Act buffer is wave-private (no barriers needed for it — proven r10);
// barriers only fence wbuf restaging. seg materialized (cls separate).
__global__ __launch_bounds__(256, 4) void k_scales(
    const float* __restrict__ samp, const unsigned short* __restrict__ iap,
    const int* __restrict__ win_p, const int* __restrict__ win_s,
    const int* __restrict__ win_c, const int* __restrict__ p2i,
    const int* __restrict__ ci, const float* __restrict__ imgf,
    const unsigned short* __restrict__ lwT, const float* __restrict__ lb,
    const unsigned short* __restrict__ f1T, const float* __restrict__ f1b,
    const unsigned short* __restrict__ f2T, const float* __restrict__ f2b,
    unsigned short* __restrict__ seg){
  __shared__ char lds[32768];
  char* wbuf = lds;
  char* actL = lds + 16384;
  const int i  = blockIdx.x & 3;
  const int rb = blockIdx.x >> 2;
  const int tid = threadIdx.x;
  const int lane = tid & 63, wv = tid >> 6;
  const int rl = lane & 15, kg = lane >> 4;
  const int kgo = kg * 8;
  const int rowBase = rb * 64 + wv * 16;
  const int row = rowBase + rl;
  const bool rv = row < BM_;
  const int lr = wv * 16 + rl;
  const int myswz = (lr & 7) << 4;

  int sj = -1, pj = -1;
  if (rv){
    int b = row >= M_;
    int g = win_c[ci[b * N_ + p2i[row]]];
    sj = win_s[g]; pj = win_p[g];
  }
  // A-frags: leaner input = samp_i[sj] + iap[pj]
  bfrag8 afrL[4];
  {
    const float* sp = samp + ((size_t)i * BS_ + (sj < 0 ? 0 : sj)) * HID_;
    const unsigned short* pp = iap + (size_t)(pj < 0 ? 0 : pj) * HID_;
    #pragma unroll
    for (int kc = 0; kc < 4; kc++){
      int k0 = kc * 32 + kgo;
      facc4 s0 = {0,0,0,0}, s1 = {0,0,0,0};
      if (sj >= 0){ s0 = *(const facc4*)(sp + k0); s1 = *(const facc4*)(sp + k0 + 4); }
      float g0=0,g1=0,g2=0,g3=0,g4=0,g5=0,g6=0,g7=0;
      if (pj >= 0){
        usvec4 u0 = *(const usvec4*)(pp + k0);
        usvec4 u1 = *(const usvec4*)(pp + k0 + 4);
        g0=bf2f(u0.x); g1=bf2f(u0.y); g2=bf2f(u0.z); g3=bf2f(u0.w);
        g4=bf2f(u1.x); g5=bf2f(u1.y); g6=bf2f(u1.z); g7=bf2f(u1.w);
      }
      bfrag8 a;
      a[0]=(short)f2bf(s0.x+g0); a[1]=(short)f2bf(s0.y+g1);
      a[2]=(short)f2bf(s0.z+g2); a[3]=(short)f2bf(s0.w+g3);
      a[4]=(short)f2bf(s1.x+g4); a[5]=(short)f2bf(s1.y+g5);
      a[6]=(short)f2bf(s1.z+g6); a[7]=(short)f2bf(s1.w+g7);
      afrL[kc] = a;
    }
  }

  // ---- leaner (two 16KB n-half stages) ----
  facc4 accL[8];
  #pragma unroll
  for (int a = 0; a < 8; a++) accL[a] = (facc4){0.f, 0.f, 0.f, 0.f};
  #pragma unroll
  for (int h = 0; h < 2; h++){
    stageW(wbuf, (const char*)(lwT + (size_t)i * 16384) + (size_t)h * 64 * 256, 256, tid);
    __syncthreads();
    mfmaHalf(&accL[h * 4], afrL, wbuf, rl, kg);
    __syncthreads();
  }
  // fl = relu(accL + lb) -> act LDS (wave-private; no barrier)
  {
    const float* bias = lb + i * HID_;
    #pragma unroll
    for (int a = 0; a < 8; a++){
      int col = (a >> 2) * 64 + (a & 3) * 16 + rl;
      float bv = bias[col];
      #pragma unroll
      for (int r = 0; r < 4; r++){
        int ar = wv * 16 + kg * 4 + r;
        float v = accL[a][r] + bv; v = v > 0.f ? v : 0.f;
        int byte = ar * 256 + col * 2;
        *(unsigned short*)(actL + (byte ^ ((ar & 7) << 4))) = f2bf(v);
      }
    }
  }
  // imgf A-frags
  bfrag8 afrI[4];
  {
    const float* a1 = imgf + ((size_t)i * BM_ + (rv ? row : 0)) * HID_;
    #pragma unroll
    for (int kc = 0; kc < 4; kc++){
      int k0 = kc * 32 + kgo;
      facc4 s0 = {0,0,0,0}, s1 = {0,0,0,0};
      if (rv){ s0 = *(const facc4*)(a1 + k0); s1 = *(const facc4*)(a1 + k0 + 4); }
      bfrag8 a;
      a[0]=(short)f2bf(s0.x); a[1]=(short)f2bf(s0.y); a[2]=(short)f2bf(s0.z); a[3]=(short)f2bf(s0.w);
      a[4]=(short)f2bf(s1.x); a[5]=(short)f2bf(s1.y); a[6]=(short)f2bf(s1.z); a[7]=(short)f2bf(s1.w);
      afrI[kc] = a;
    }
  }
  // ---- fcs1 K-half 0 (A = imgf): two n-half stages ----
  facc4 accF[8];
  #pragma unroll
  for (int a = 0; a < 8; a++) accF[a] = (facc4){0.f, 0.f, 0.f, 0.f};
  #pragma unroll
  for (int h = 0; h < 2; h++){
    stageW(wbuf, (const char*)(f1T + (size_t)i * 32768) + (size_t)h * 64 * 512, 512, tid);
    __syncthreads();
    mfmaHalf(&accF[h * 4], afrI, wbuf, rl, kg);
    __syncthreads();
  }
  // fl A-frags (wave-private act read)
  bfrag8 afrF[4];
  #pragma unroll
  for (int kc = 0; kc < 4; kc++){
    int byteA = lr * 256 + ((kc * 32 + kgo) << 1);
    afrF[kc] = *(const bfrag8*)(actL + (byteA ^ myswz));
  }
  // ---- fcs1 K-half 1 (A = fl): two n-half stages ----
  #pragma unroll
  for (int h = 0; h < 2; h++){
    stageW(wbuf, (const char*)(f1T + (size_t)i * 32768) + (size_t)h * 64 * 512 + 256, 512, tid);
    __syncthreads();
    mfmaHalf(&accF[h * 4], afrF, wbuf, rl, kg);
    __syncthreads();
  }
  // fc = accF + b1 (keep f32); bf16 copy -> act LDS
  {
    const float* bias = f1b + i * HID_;
    #pragma unroll
    for (int a = 0; a < 8; a++){
      int col = (a >> 2) * 64 + (a & 3) * 16 + rl;
      float bv = bias[col];
      #pragma unroll
      for (int r = 0; r < 4; r++){
        int ar = wv * 16 + kg * 4 + r;
        float v = accF[a][r] + bv;
        accF[a][r] = v;
        int byte = ar * 256 + col * 2;
        *(unsigned short*)(actL + (byte ^ ((ar & 7) << 4))) = f2bf(v);
      }
    }
  }
  // fc A-frags (wave-private act read)
  bfrag8 afrC[4];
  #pragma unroll
  for (int kc = 0; kc < 4; kc++){
    int byteA = lr * 256 + ((kc * 32 + kgo) << 1);
    afrC[kc] = *(const bfrag8*)(actL + (byteA ^ myswz));
  }
  // ---- fcs2: two n-half stages ----
  facc4 accT[8];
  #pragma unroll
  for (int a = 0; a < 8; a++) accT[a] = (facc4){0.f, 0.f, 0.f, 0.f};
  #pragma unroll
  for (int h = 0; h < 2; h++){
    stageW(wbuf, (const char*)(f2T + (size_t)i * 16384) + (size_t)h * 64 * 256, 256, tid);
    __syncthreads();
    mfmaHalf(&accT[h * 4], afrC, wbuf, rl, kg);
    __syncthreads();
  }
  // gate + seg store: seg[:, i*128+col] = relu(fc * sigmoid(accT + b2))
  {
    const float* bias2 = f2b + i * HID_;
    #pragma unroll
    for (int a = 0; a < 8; a++){
      int col = (a >> 2) * 64 + (a & 3) * 16 + rl;
      float bv2 = bias2[col];
      #pragma unroll
      for (int r = 0; r < 4; r++){
        int orow = rowBase + kg * 4 + r;
        if (orow < BM_){
          float tv = accT[a][r] + bv2;
          float fw = 1.f / (1.f + expf(-tv));
          float u = accF[a][r] * fw;
          u = u > 0.f ? u : 0.f;
          seg[(size_t)orow * (NSC_ * HID_) + i * HID_ + col] = f2bf(u);
        }
      }
    }
  }
}

// ---------------------------------------------------------------------------
// Classifier: logits = relu(seg @ W1 + b1) @ W2 + b2.
// W1 staged as 8 x 16KB (4 k-quarters x 2 n-halves); LDS 32KB, 5 blocks/CU.
__global__ __launch_bounds__(256, 4) void k_cls(const unsigned short* __restrict__ seg,
    const unsigned short* __restrict__ c1T, const float* __restrict__ c1b,
    const unsigned short* __restrict__ c2T, const float* __restrict__ c2b,
    float* __restrict__ logits){
  __shared__ char lds[32768];
  char* wbuf = lds;
  char* actL = lds + 16384;
  const int tid = threadIdx.x;
  const int lane = tid & 63, wv = tid >> 6;
  const int rl = lane & 15, kg = lane >> 4;
  const int kgo = kg * 8;
  const int rowBase = blockIdx.x * 64 + wv * 16;
  const int row = rowBase + rl;
  const bool rv = row < BM_;
  const unsigned short* ar = seg + (size_t)(rv ? row : 0) * 512;
  facc4 acc[8];
  #pragma unroll
  for (int a = 0; a < 8; a++) acc[a] = (facc4){0.f, 0.f, 0.f, 0.f};
  #pragma unroll 1
  for (int ph = 0; ph < 4; ph++){
    bfrag8 afrQ[4];
    #pragma unroll
    for (int kc = 0; kc < 4; kc++){
      bfrag8 a = (bfrag8){0,0,0,0,0,0,0,0};
      if (rv) a = *(const bfrag8*)(ar + ph * 128 + kc * 32 + kgo);
      afrQ[kc] = a;
    }
    #pragma unroll
    for (int h = 0; h < 2; h++){
      stageW(wbuf, (const char*)c1T + (size_t)h * 64 * 1024 + ph * 256, 1024, tid);
      __syncthreads();
      mfmaHalf(&acc[h * 4], afrQ, wbuf, rl, kg);
      __syncthreads();
    }
  }
  // hid = relu(acc + c1b) -> act; stage W2; dot
  #pragma unroll
  for (int a = 0; a < 8; a++){
    int col = (a >> 2) * 64 + (a & 3) * 16 + rl;
    float bv = c1b[col];
    #pragma unroll
    for (int r = 0; r < 4; r++){
      int arr = wv * 16 + kg * 4 + r;
      float v = acc[a][r] + bv; v = v > 0.f ? v : 0.f;
      int byte = arr * 256 + col * 2;
      *(unsigned short*)(actL + (byte ^ ((arr & 7) << 4))) = f2bf(v);
    }
  }
  for (int c = tid; c < 320; c += 256)
    *(bfrag8*)(wbuf + (c << 4)) = *(const bfrag8*)((const char*)c2T + (c << 4));
  __syncthreads();
  {
    int lrd = tid >> 2, n0 = (tid & 3) * 5;
    int orow = blockIdx.x * 64 + lrd;
    if (orow < BM_){
      float accD[5];
      #pragma unroll
      for (int q = 0; q < 5; q++) accD[q] = c2b[n0 + q];
      #pragma unroll
      for (int k8 = 0; k8 < 16; k8++){
        int byteA = lrd * 256 + (k8 << 4);
        bfrag8 hv = *(const bfrag8*)(actL + (byteA ^ ((lrd & 7) << 4)));
        #pragma unroll
        for (int q = 0; q < 5; q++){
          bfrag8 w8 = *(const bfrag8*)(wbuf + (n0 + q) * 256 + (k8 << 4));
          #pragma unroll
          for (int e = 0; e < 8; e++)
            accD[q] += bf2f((unsigned short)hv[e]) * bf2f((unsigned short)w8[e]);
        }
      }
      #pragma unroll
      for (int q = 0; q < 5; q++)
        logits[(size_t)orow * NCLS_ + n0 + q] = accD[q];
    }
  }
}

// ---------------------------------------------------------------------------
extern "C" void kernel_launch(void* const* d_in, const int* in_sizes, int n_in,
                              void* d_out, int out_size, void* d_ws, size_t ws_size,
                              hipStream_t stream){
  const float* samp = (const float*)d_in[1];   // pts_sample_feat (pts_feat_layers is dead)
  const float* img  = (const float*)d_in[2];
  const float* imgf = (const float*)d_in[3];
  const float* lW   = (const float*)d_in[4];
  const float* lb   = (const float*)d_in[5];
  const float* f1W  = (const float*)d_in[6];
  const float* f1b  = (const float*)d_in[7];
  const float* f2W  = (const float*)d_in[8];
  const float* f2b  = (const float*)d_in[9];
  const float* c1W  = (const float*)d_in[10];
  const float* c1b  = (const float*)d_in[11];
  const float* c2W  = (const float*)d_in[12];
  const float* c2b  = (const float*)d_in[13];
  const int* ptsimg = (const int*)d_in[14];
  const int* p2i    = (const int*)d_in[15];
  const int* si     = (const int*)d_in[16];
  const int* ci     = (const int*)d_in[17];

  char* ws = (char*)d_ws;
  int*   win_p = (int*)(ws + 0);                       //   960,000 B
  int*   win_s = (int*)(ws + 960000);                  //   960,000 B
  int*   win_c = (int*)(ws + 1920000);                 //   400,000 B
  unsigned short* iap = (unsigned short*)(ws + 2320128);    // 15,360,000 B
  unsigned short* seg = (unsigned short*)(ws + 17680384);   // 61,440,000 B
  unsigned short* lwT = (unsigned short*)(ws + 79120512);   // 131,072 B
  unsigned short* f1T = lwT + 65536;                        // 262,144 B
  unsigned short* f2T = f1T + 131072;                       // 131,072 B
  unsigned short* c1T = f2T + 65536;                        // 131,072 B
  unsigned short* c2T = c1T + 65536;                        //   5,120 B

  float* logits = (float*)d_out;
  float* o3d    = (float*)d_out + (size_t)BM_ * NCLS_;

  (void)hipMemsetAsync(ws, 0xFF, 2320000, stream);     // win_* = -1
  k_front  <<<5978,  256, 0, stream>>>(img, ptsimg, iap, p2i, si, ci,
                                       win_p, win_s, win_c,
                                       lW, f1W, f2W, c1W, c2W,
                                       lwT, f1T, f2T, c1T, c2T);
  k_o3d    <<<7500,  256, 0, stream>>>(samp, win_s, win_p, iap, o3d);
  k_scales <<<3752,  256, 0, stream>>>(samp, iap, win_p, win_s, win_c, p2i, ci,
                                       imgf, lwT, lb, f1T, f1b, f2T, f2b, seg);
  k_cls    <<<938,   256, 0, stream>>>(seg, c1T, c1b, c2T, c2b, logits);
}